// Round 1
// baseline (31.038 us; speedup 1.0000x reference)
//
#include <hip/hip_runtime.h>
#include <math.h>

// Chamfer distance, B=8, N=M=4096, D=3, fp32.
// d(a,b) = ||a||^2 + ||b||^2 - 2 a.b ; per a-point take min over b, sqrt, mean.
// Factored: dist1[n] = max(sq1[n] + min_m(sq2[m] - 2 a.b[m]), 0)
// Inner pair cost: 3 FMA + 1 min (VALU-bound; no fp32 MFMA on CDNA4).

#define NPTS 4096
#define BATCH 8
#define PA 4                       // a-points per thread (register-blocked)
#define SPLIT 8                    // M-segments per point (lane bits 0..2)
#define SEGLEN (NPTS / SPLIT)      // 512
#define SEGPAD (SEGLEN + 1)        // 513 -> bank-conflict-free across segs
#define PTS_PER_BLOCK ((256 / SPLIT) * PA)        // 128
#define BLOCKS_PER_BN (NPTS / PTS_PER_BLOCK)      // 32
#define BLOCKS_PER_DIR (BATCH * BLOCKS_PER_BN)    // 256

__global__ __launch_bounds__(256, 2) void chamfer_min_kernel(
    const float* __restrict__ pcs1, const float* __restrict__ pcs2,
    float* __restrict__ partials)
{
    // float4 per b-point: (x, y, z, ||b||^2). 8 segs * 513 * 16B = 64.1 KB.
    // addr/4 = 2052*seg + 4k ; 2052%32==4 -> segs land on 8 distinct
    // 4-bank groups -> conflict-free ds_read_b128 (16 lanes/seg broadcast).
    __shared__ float4 bpts[SPLIT * SEGPAD];
    __shared__ float wavesum[4];

    const int bid   = blockIdx.x;
    const int dir   = bid >> 8;        // 0: A=pcs1,B=pcs2 ; 1: swapped
    const int r     = bid & 255;
    const int b     = r >> 5;          // batch
    const int chunk = r & 31;          // 128-point chunk of the A side

    const float* A  = (dir == 0) ? pcs1 : pcs2;
    const float* Bp = (dir == 0) ? pcs2 : pcs1;
    const float* abase = A  + (size_t)b * NPTS * 3;
    const float* bbase = Bp + (size_t)b * NPTS * 3;

    const int tid = threadIdx.x;

    // ---- stage B side into LDS (once; inputs are L2-resident) ----
    for (int m = tid; m < NPTS; m += 256) {
        float x = bbase[m * 3 + 0];
        float y = bbase[m * 3 + 1];
        float z = bbase[m * 3 + 2];
        float sq = x * x + y * y + z * z;
        bpts[(m >> 9) * SEGPAD + (m & 511)] = make_float4(x, y, z, sq);
    }

    // ---- per-thread A points (registers) ----
    const int seg = tid & 7;
    const int pg  = tid >> 3;                    // 0..31
    const int apt = chunk * PTS_PER_BLOCK + pg * PA;

    float nax[PA], nay[PA], naz[PA], sq1[PA], tmin[PA];
#pragma unroll
    for (int p = 0; p < PA; ++p) {
        float x = abase[(apt + p) * 3 + 0];
        float y = abase[(apt + p) * 3 + 1];
        float z = abase[(apt + p) * 3 + 2];
        sq1[p]  = x * x + y * y + z * z;
        nax[p]  = -2.0f * x;
        nay[p]  = -2.0f * y;
        naz[p]  = -2.0f * z;
        tmin[p] = 3.4e38f;
    }
    __syncthreads();

    // ---- main loop: 512 iters, 1 ds_read_b128 + 16 VALU each ----
    const float4* bs = &bpts[seg * SEGPAD];
#pragma unroll 4
    for (int k = 0; k < SEGLEN; ++k) {
        float4 q = bs[k];
#pragma unroll
        for (int p = 0; p < PA; ++p) {
            float t = fmaf(nax[p], q.x,
                      fmaf(nay[p], q.y,
                      fmaf(naz[p], q.z, q.w)));
            tmin[p] = fminf(tmin[p], t);
        }
    }

    // ---- min across the 8 segments (lane bits 0..2) ----
#pragma unroll
    for (int off = 1; off < 8; off <<= 1) {
#pragma unroll
        for (int p = 0; p < PA; ++p)
            tmin[p] = fminf(tmin[p], __shfl_xor(tmin[p], off, 64));
    }

    // ---- sqrt + sum (seg==0 lanes carry, others contribute 0) ----
    float s = 0.0f;
    if (seg == 0) {
#pragma unroll
        for (int p = 0; p < PA; ++p) {
            float d = fmaxf(sq1[p] + tmin[p], 0.0f);  // clamp cancellation
            s += sqrtf(d);
        }
    }
#pragma unroll
    for (int off = 1; off < 64; off <<= 1)
        s += __shfl_xor(s, off, 64);

    const int wave = tid >> 6;
    if ((tid & 63) == 0) wavesum[wave] = s;
    __syncthreads();
    if (tid == 0)
        partials[bid] = wavesum[0] + wavesum[1] + wavesum[2] + wavesum[3];
}

__global__ void chamfer_final_kernel(const float* __restrict__ partials,
                                     float* __restrict__ out)
{
    __shared__ float ws[4];
    const int t = threadIdx.x;
    float v = partials[t] + partials[t + 256];
#pragma unroll
    for (int off = 1; off < 64; off <<= 1)
        v += __shfl_xor(v, off, 64);
    if ((t & 63) == 0) ws[t >> 6] = v;
    __syncthreads();
    if (t == 0)
        out[0] = (ws[0] + ws[1] + ws[2] + ws[3]) * (1.0f / 65536.0f);
    // loss = 0.5 * (sum1/32768 + sum2/32768) = (sum1+sum2)/65536
}

extern "C" void kernel_launch(void* const* d_in, const int* in_sizes, int n_in,
                              void* d_out, int out_size, void* d_ws, size_t ws_size,
                              hipStream_t stream) {
    const float* pcs1 = (const float*)d_in[0];
    const float* pcs2 = (const float*)d_in[1];
    float* out      = (float*)d_out;
    float* partials = (float*)d_ws;   // 512 floats = 2 KB scratch

    chamfer_min_kernel<<<dim3(2 * BLOCKS_PER_DIR), dim3(256), 0, stream>>>(
        pcs1, pcs2, partials);
    chamfer_final_kernel<<<dim3(1), dim3(256), 0, stream>>>(partials, out);
}